// Round 18
// baseline (1076.026 us; speedup 1.0000x reference)
//
#include <hip/hip_runtime.h>

// Fused StyleGAN2 conv_downsample_2d, f32, register-FIR, fine-grained blocks.
//   out[n,oc,oh,ow] = sum_c w[c,oc] * y[n,c,2oh,2ow]
//   y = separable FIR {1,3,3,1}/8 (vert) x {1,3,3,1}/8 (horiz), pad=1
//
// Design ledger (r1-r17):
//  - bf16 MFMA: precision-independent ~0.7 absmax (r2/3/5) -> f32 VALU.
//  - NEVER pass __launch_bounds__ min-waves arg (r6/r8 spilled).
//  - Exonerated: bank conflicts (r12: 0), LDS instr count (r14), manual
//    2-deep pipelines (r13: slower), barrier frequency (r17: null),
//    occupancy per se (r8: 87% slow).
//  - Remaining theory: only 2 independent barrier groups/CU -> barrier
//    drain/skew uncoverable -> VALU 43%. This round: 256-thr blocks with
//    VGPR <= 64 target -> up to 8 independent groups/CU; w via broadcast
//    vector loads (removes SMEM from inner loop -> precise waitcnts).
//
// Block 256 thr = 4 waves. Tile: 256 oc x (2 oh x 16 ow). Wave wv covers oc
// [wv*64,(wv+1)*64) as 2 half-strips (hi = lane>>5, 32 oc each); lane sp =
// (ohl = (lane>>4)&1, owl = lane&15). 16 chunks of 8 ch; wave stages
// channels {2wv, 2wv+1}: lanes 0..33 own patch cols (6 rows), vFIR in regs.

#define VS 35   // v_s col pitch (odd; 0 conflicts measured r12/r14/r17)

typedef __attribute__((ext_vector_type(4))) float f32x4;

__global__ __launch_bounds__(256)
void fused_downconv_v12(const float* __restrict__ x, const float* __restrict__ w,
                        float* __restrict__ out) {
    __shared__ __align__(16) float v_s[2 * 8 * 2 * VS];   // 4480 B

    const int tid  = threadIdx.x;
    const int lane = tid & 63;
    const int wv   = tid >> 6;          // wave id 0..3
    const int hi   = lane >> 5;         // oc half-strip within wave
    const int ocb  = wv * 64 + hi * 32; // this lane's 32-oc base
    const int cha  = 2 * wv;            // staged channels within chunk
    const int chb  = 2 * wv + 1;

    const int ow0 = blockIdx.x * 16;
    const int oh0 = blockIdx.y * 2;
    const int n   = blockIdx.z;

    const int rbase = 4 * blockIdx.y - 1;
    const int cbase = 2 * ow0 - 1;

    // ---- staging map: lane<34 owns col cbase+lane, rows rbase..rbase+5 ----
    int off[6];
    unsigned ldmask = 0;
    {
        int gc = cbase + lane;
        bool cok = (lane < 34) && ((unsigned)gc < 512u);
        #pragma unroll
        for (int k = 0; k < 6; k++) {
            int gr = rbase + k;
            bool ok = cok && ((unsigned)gr < 512u);
            off[k] = ok ? (gr * 512 + gc) : 0;
            if (ok) ldmask |= 1u << k;
        }
    }

    const int owl = lane & 15;          // GEMM spatial mapping
    const int ohl = (lane >> 4) & 1;

    float xrA[6], xrB[6];
    float acc[32];
    #pragma unroll
    for (int i = 0; i < 32; i++) acc[i] = 0.f;

    auto prefetch = [&](int c0) {
        const float* xa = x + ((size_t)(n * 128 + c0 + cha)) * 262144;
        const float* xb = x + ((size_t)(n * 128 + c0 + chb)) * 262144;
        #pragma unroll
        for (int k = 0; k < 6; k++) {
            xrA[k] = ((ldmask >> k) & 1u) ? xa[off[k]] : 0.f;
            xrB[k] = ((ldmask >> k) & 1u) ? xb[off[k]] : 0.f;
        }
    };
    auto vwrite = [&](int buf) {
        if (lane < 34) {
            #pragma unroll
            for (int o = 0; o < 2; o++) {
                float va = 0.125f * (xrA[2 * o] + xrA[2 * o + 3])
                         + 0.375f * (xrA[2 * o + 1] + xrA[2 * o + 2]);
                float vb = 0.125f * (xrB[2 * o] + xrB[2 * o + 3])
                         + 0.375f * (xrB[2 * o + 1] + xrB[2 * o + 2]);
                v_s[((buf * 8 + cha) * 2 + o) * VS + lane] = va;
                v_s[((buf * 8 + chb) * 2 + o) * VS + lane] = vb;
            }
        }
    };

    prefetch(0);
    vwrite(0);
    prefetch(8);
    __syncthreads();

    for (int t = 0; t < 16; t++) {
        const int buf = t & 1;
        if (t < 15) {
            vwrite(buf ^ 1);                   // chunk t+1 -> other buffer
            if (t < 14) prefetch((t + 2) * 8); // issue loads for chunk t+2
        }
        // ---- GEMM over the 8 channels of chunk t ----
        #pragma unroll
        for (int cc = 0; cc < 8; cc++) {
            const float* vp = &v_s[((buf * 8 + cc) * 2 + ohl) * VS + 2 * owl];
            float v0 = vp[0], v1 = vp[1], v2 = vp[2], v3 = vp[3];
            float y = 0.125f * (v0 + v3) + 0.375f * (v1 + v2);
            // broadcast vector loads: uniform within each 32-lane half
            const float* wrow = w + ((t * 8 + cc) << 8) + ocb;
            #pragma unroll
            for (int q = 0; q < 8; q++) {
                f32x4 wq = *(const f32x4*)&wrow[q * 4];
                acc[q * 4 + 0] = fmaf(wq.x, y, acc[q * 4 + 0]);
                acc[q * 4 + 1] = fmaf(wq.y, y, acc[q * 4 + 1]);
                acc[q * 4 + 2] = fmaf(wq.z, y, acc[q * 4 + 2]);
                acc[q * 4 + 3] = fmaf(wq.w, y, acc[q * 4 + 3]);
            }
        }
        __syncthreads();   // v-writes(t+1) visible; GEMM(t) reads drained
    }

    // ---- epilogue: oc = ocb+i, oh = oh0+ohl, ow = ow0+owl ----
    {
        size_t base = (((size_t)n * 256 + ocb) * 256 + (size_t)(oh0 + ohl)) * 256
                      + ow0 + owl;
        #pragma unroll
        for (int i = 0; i < 32; i++)
            out[base + (size_t)i * 65536] = acc[i];
    }
}

extern "C" void kernel_launch(void* const* d_in, const int* in_sizes, int n_in,
                              void* d_out, int out_size, void* d_ws, size_t ws_size,
                              hipStream_t stream) {
    const float* x = (const float*)d_in[0];
    const float* w = (const float*)d_in[1];
    float* out = (float*)d_out;

    dim3 grid(16, 128, 4);   // ow-tiles(16 wide), oh-tiles(2 tall), n
    dim3 block(256);
    hipLaunchKernelGGL(fused_downconv_v12, grid, block, 0, stream, x, w, out);
}

// Round 19
// 419.271 us; speedup vs baseline: 2.5664x; 2.5664x over previous
//
#include <hip/hip_runtime.h>

// Fused StyleGAN2 conv_downsample_2d, f32, register-FIR + SGPR-w GEMM.
// r12 skeleton + two targeted stall fixes:
//  (1) GEMM phase-split: all 32 v-tap ds_reads issued up-front into named
//      registers (counted lgkmcnt, no per-cc ds/smem drain interleave),
//      then 8 y-FIRs, then a pure s_load(w)+FMA stream.
//  (2) prefetch fast paths: full-mask lanes load plain (no cndmask);
//      zero-mask lanes (34..63, interior) issue NO loads (r12 wasted 47%
//      of staging VMEM slots on dummy xb[0] loads).
//   out[n,oc,oh,ow] = sum_c w[c,oc] * y[n,c,2oh,2ow]
//   y = separable FIR {1,3,3,1}/8 (vert) x {1,3,3,1}/8 (horiz), pad=1
//
// Design ledger (r1-r18):
//  - bf16 MFMA: precision-independent ~0.7 absmax (r2/3/5) -> f32 VALU.
//  - NEVER pass __launch_bounds__ min-waves arg (r6/r8 spilled).
//  - w MUST be s_load/SGPR broadcast (r18: per-lane vector w = 2.6x slower).
//  - Exonerated: bank conflicts (r12: 0), LDS instr width (r14), manual
//    2-deep pipelines (r13), barrier frequency (r17), occupancy (r8/r16).
//  - Diagnosis of the 412us plateau: lgkmcnt drains mixing ds_read(y) with
//    s_load(w) per-cc, + dummy staging loads. This round isolates both.
//
// Block 512 thr = 8 waves. Tile: 256 oc x (4 oh x 16 ow). Wave = 32-oc strip,
// lane = one of 64 sp. 16 chunks of 8 ch; wave wv stages channel c0+wv:
// lanes 0..33 own patch columns (10 rows x 34 cols), vertical FIR in regs.

#define VS 35   // v_s col pitch (odd; 0 bank conflicts measured r12/r14/r17)

__global__ __launch_bounds__(512)
void fused_downconv_v13(const float* __restrict__ x, const float* __restrict__ w,
                        float* __restrict__ out) {
    __shared__ __align__(16) float v_s[2 * 8 * 4 * VS];   // 8960 B

    const int tid  = threadIdx.x;
    const int lane = tid & 63;
    const int wv   = tid >> 6;   // wave id: staged channel offset, oc strip
    const int oc0  = __builtin_amdgcn_readfirstlane((tid >> 6) << 5);

    const int ow0 = blockIdx.x * 16;
    const int oh0 = blockIdx.y * 4;
    const int n   = blockIdx.z;

    const int rbase = 2 * oh0 - 1;
    const int cbase = 2 * ow0 - 1;

    // ---- staging map: lane<34 owns col cbase+lane, rows rbase..rbase+9 ----
    int off[10];
    unsigned ldmask = 0;
    {
        int gc = cbase + lane;
        bool cok = (lane < 34) && ((unsigned)gc < 512u);
        #pragma unroll
        for (int k = 0; k < 10; k++) {
            int gr = rbase + k;
            bool ok = cok && ((unsigned)gr < 512u);
            off[k] = ok ? (gr * 512 + gc) : 0;
            if (ok) ldmask |= 1u << k;
        }
    }

    const int owl = lane & 15;   // GEMM spatial mapping: lane = sp
    const int ohl = lane >> 4;

    float xr[10];
    float acc[32];
    #pragma unroll
    for (int i = 0; i < 32; i++) acc[i] = 0.f;

    auto prefetch = [&](int c0) {
        const float* xb = x + ((size_t)(n * 128 + c0 + wv)) * 262144;
        if (ldmask == 0x3FFu) {
            // full lane: plain loads, no cndmask
            #pragma unroll
            for (int k = 0; k < 10; k++) xr[k] = xb[off[k]];
        } else if (ldmask == 0u) {
            // idle lane (34..63, or fully OOB): no loads at all
            #pragma unroll
            for (int k = 0; k < 10; k++) xr[k] = 0.f;
        } else {
            // border lane: masked loads
            #pragma unroll
            for (int k = 0; k < 10; k++)
                xr[k] = ((ldmask >> k) & 1u) ? xb[off[k]] : 0.f;
        }
    };
    auto vwrite = [&](int buf) {
        if (lane < 34) {
            #pragma unroll
            for (int o = 0; o < 4; o++) {
                float v = 0.125f * (xr[2 * o] + xr[2 * o + 3])
                        + 0.375f * (xr[2 * o + 1] + xr[2 * o + 2]);
                v_s[((buf * 8 + wv) * 4 + o) * VS + lane] = v;
            }
        }
    };

    prefetch(0);
    vwrite(0);
    prefetch(8);
    __syncthreads();

    const int vrd = ohl * VS + 2 * owl;   // per-lane v_s read base (within cc row)

    for (int t = 0; t < 16; t++) {
        const int buf = t & 1;
        if (t < 15) {
            vwrite(buf ^ 1);                  // chunk t+1 -> other buffer
            if (t < 14) prefetch((t + 2) * 8); // issue loads for chunk t+2
        }
        // ---- GEMM phase 1: batch all 32 v-tap reads into registers ----
        float pa[8], pb[8], pc[8], pd[8];
        #pragma unroll
        for (int cc = 0; cc < 8; cc++) {
            const float* vp = &v_s[(buf * 8 + cc) * 4 * VS + vrd];
            pa[cc] = vp[0]; pb[cc] = vp[1]; pc[cc] = vp[2]; pd[cc] = vp[3];
        }
        // ---- GEMM phase 2: 8 horizontal FIRs ----
        float yv[8];
        #pragma unroll
        for (int cc = 0; cc < 8; cc++)
            yv[cc] = 0.125f * (pa[cc] + pd[cc]) + 0.375f * (pb[cc] + pc[cc]);
        // ---- GEMM phase 3: pure s_load(w) + FMA stream ----
        #pragma unroll
        for (int cc = 0; cc < 8; cc++) {
            const float* wrow = w + ((t * 8 + cc) << 8) + oc0;  // wave-uniform -> s_load
            #pragma unroll
            for (int i = 0; i < 32; i++)
                acc[i] = fmaf(wrow[i], yv[cc], acc[i]);
        }
        __syncthreads();   // v-writes(t+1) visible; GEMM(t) reads drained
    }

    // ---- epilogue: oc = oc0+i, oh = oh0+ohl, ow = ow0+owl ----
    {
        size_t base = (((size_t)n * 256 + oc0) * 256 + (size_t)(oh0 + ohl)) * 256
                      + ow0 + owl;
        #pragma unroll
        for (int i = 0; i < 32; i++)
            out[base + (size_t)i * 65536] = acc[i];
    }
}

extern "C" void kernel_launch(void* const* d_in, const int* in_sizes, int n_in,
                              void* d_out, int out_size, void* d_ws, size_t ws_size,
                              hipStream_t stream) {
    const float* x = (const float*)d_in[0];
    const float* w = (const float*)d_in[1];
    float* out = (float*)d_out;

    dim3 grid(16, 64, 4);   // ow-tiles(16 wide), oh-tiles(4 tall), n
    dim3 block(512);
    hipLaunchKernelGGL(fused_downconv_v13, grid, block, 0, stream, x, w, out);
}

// Round 20
// 360.002 us; speedup vs baseline: 2.9889x; 1.1646x over previous
//
#include <hip/hip_runtime.h>

// Fused StyleGAN2 conv_downsample_2d — TWO-PASS structure (r20).
//   y[n,c,oh,ow] = separable FIR {1,3,3,1}/8 x {1,3,3,1}/8 (pad 1) of x, at even taps
//   out[n,oc,oh,ow] = sum_c w[c,oc] * y[n,c,oh,ow]
//
// Design ledger (r1-r19):
//  - bf16 MFMA on this op: ~4.4% per-term internal noise (e4m3-class),
//    precision-split-invariant (r2/3/5) -> absmax ~0.7 > 0.4325. f32 only.
//  - NEVER pass __launch_bounds__ min-waves arg (r6/r8 spilled).
//  - w must be SGPR/s_load broadcast (r18: vector w loads 2.6x slower).
//  - Fused single-kernel family plateaus at 412 us (r12) with VALU ~46%,
//    HBM ~28%, no counter saturated; every in-place fix nulled (r13-r19).
//    Cause: correlated phase stalls behind barriers. This round de-correlates:
//    pass 1 = pure-BW FIR into d_ws; pass 2 = barrier-free, LDS-free GEMM
//    whose FMA stream runs uninterrupted (floor 109 us).
//  - Fallback: if ws_size < 134 MB, launch the proven r12 fused kernel.

typedef __attribute__((ext_vector_type(4))) float f32x4;

// ---------------------------------------------------------------- pass 1: FIR
// Block = 256 thr; blockIdx.x linear = nc*32 + gh  (nc = n*128+c, gh = oh/8).
// Phase A: v[oh_l][col] = vertical FIR, direct from global (coalesced cols).
// Phase B: y[oh_l][ow] = horizontal FIR from v_lds (2-way banks), store.
__global__ __launch_bounds__(256)
void fir_pass(const float* __restrict__ x, float* __restrict__ y) {
    __shared__ float vlds[8][516];   // cols -1..512 stored at +1; 16.5 KB

    const int tid = threadIdx.x;
    const int b   = blockIdx.x;
    const int gh  = b & 31;          // oh group (8 rows)
    const int nc  = b >> 5;          // n*128 + c

    const float* xim = x + (size_t)nc * 262144;

    // zero the horizontal pad slots
    if (tid < 8)       vlds[tid][0]   = 0.f;
    else if (tid < 16) vlds[tid - 8][513] = 0.f;

    const int col = tid & 255;       // this thread: cols {col, col+256}
    const bool interior = (gh >= 1) && (gh <= 30);

    #pragma unroll
    for (int ohl = 0; ohl < 8; ohl++) {
        const int rb = 2 * (gh * 8 + ohl) - 1;
        #pragma unroll
        for (int h = 0; h < 2; h++) {
            const int c2 = col + h * 256;
            float s0, s1, s2, s3;
            if (interior) {
                const float* p = xim + (size_t)rb * 512 + c2;
                s0 = p[0]; s1 = p[512]; s2 = p[1024]; s3 = p[1536];
            } else {
                s0 = ((unsigned)(rb + 0) < 512u) ? xim[(size_t)(rb + 0) * 512 + c2] : 0.f;
                s1 = ((unsigned)(rb + 1) < 512u) ? xim[(size_t)(rb + 1) * 512 + c2] : 0.f;
                s2 = ((unsigned)(rb + 2) < 512u) ? xim[(size_t)(rb + 2) * 512 + c2] : 0.f;
                s3 = ((unsigned)(rb + 3) < 512u) ? xim[(size_t)(rb + 3) * 512 + c2] : 0.f;
            }
            vlds[ohl][1 + c2] = 0.125f * (s0 + s3) + 0.375f * (s1 + s2);
        }
    }
    __syncthreads();

    // Phase B: thread -> oh_l = tid>>5, ow = (tid&31) + 32j
    const int ohl = tid >> 5;
    const int owb = tid & 31;
    float* yrow = y + ((size_t)nc * 256 + (size_t)(gh * 8 + ohl)) * 256;
    #pragma unroll
    for (int j = 0; j < 8; j++) {
        const int ow = owb + 32 * j;
        const float* vb = &vlds[ohl][2 * ow];   // taps at cols 2ow-1..2ow+2 (+1 shift)
        yrow[ow] = 0.125f * (vb[0] + vb[3]) + 0.375f * (vb[1] + vb[2]);
    }
}

// -------------------------------------------------------------- pass 2: GEMM
// Block = 512 thr = 8 waves; wave wv -> oc strip [wv*32, wv*32+32) (s_load w);
// lane = one of 64 spatial points. No LDS, no barriers: uninterrupted K=128
// stream of {1 coalesced y load + 32 FMA}.
__global__ __launch_bounds__(512)
void gemm_pass(const float* __restrict__ yws, const float* __restrict__ w,
               float* __restrict__ out) {
    const int tid  = threadIdx.x;
    const int lane = tid & 63;
    const int oc0  = __builtin_amdgcn_readfirstlane((tid >> 6) << 5);

    const int n    = blockIdx.y;
    const int ohw0 = blockIdx.x * 64;

    const float* yb = yws + ((size_t)n * 128) * 65536 + ohw0 + lane;
    const float* wb = w + oc0;

    float acc[32];
    #pragma unroll
    for (int i = 0; i < 32; i++) acc[i] = 0.f;

    #pragma unroll 8
    for (int c = 0; c < 128; ++c) {
        const float yv = yb[(size_t)c << 16];
        const float* wr = wb + (c << 8);          // wave-uniform -> s_load
        #pragma unroll
        for (int i = 0; i < 32; i++)
            acc[i] = fmaf(wr[i], yv, acc[i]);
    }

    const size_t ob = ((size_t)n * 256 + oc0) * 65536 + ohw0 + lane;
    #pragma unroll
    for (int i = 0; i < 32; i++)
        out[ob + (size_t)i * 65536] = acc[i];
}

// ------------------------------------------------- fallback: r12 fused (412us)
#define VS 35
__global__ __launch_bounds__(512)
void fused_fallback(const float* __restrict__ x, const float* __restrict__ w,
                    float* __restrict__ out) {
    __shared__ __align__(16) float v_s[2 * 8 * 4 * VS];

    const int tid  = threadIdx.x;
    const int lane = tid & 63;
    const int wv   = tid >> 6;
    const int oc0  = __builtin_amdgcn_readfirstlane((tid >> 6) << 5);

    const int ow0 = blockIdx.x * 16;
    const int oh0 = blockIdx.y * 4;
    const int n   = blockIdx.z;

    const int rbase = 2 * oh0 - 1;
    const int cbase = 2 * ow0 - 1;

    int off[10];
    unsigned ldmask = 0;
    {
        int gc = cbase + lane;
        bool cok = (lane < 34) && ((unsigned)gc < 512u);
        #pragma unroll
        for (int k = 0; k < 10; k++) {
            int gr = rbase + k;
            bool ok = cok && ((unsigned)gr < 512u);
            off[k] = ok ? (gr * 512 + gc) : 0;
            if (ok) ldmask |= 1u << k;
        }
    }

    const int owl = lane & 15;
    const int ohl = lane >> 4;

    float xr[10];
    float acc[32];
    #pragma unroll
    for (int i = 0; i < 32; i++) acc[i] = 0.f;

    auto prefetch = [&](int c0) {
        const float* xb = x + ((size_t)(n * 128 + c0 + wv)) * 262144;
        #pragma unroll
        for (int k = 0; k < 10; k++)
            xr[k] = ((ldmask >> k) & 1u) ? xb[off[k]] : 0.f;
    };
    auto vwrite = [&](int buf) {
        if (lane < 34) {
            #pragma unroll
            for (int o = 0; o < 4; o++) {
                float v = 0.125f * (xr[2 * o] + xr[2 * o + 3])
                        + 0.375f * (xr[2 * o + 1] + xr[2 * o + 2]);
                v_s[((buf * 8 + wv) * 4 + o) * VS + lane] = v;
            }
        }
    };

    prefetch(0);
    vwrite(0);
    prefetch(8);
    __syncthreads();

    for (int t = 0; t < 16; t++) {
        const int buf = t & 1;
        if (t < 15) {
            vwrite(buf ^ 1);
            if (t < 14) prefetch((t + 2) * 8);
        }
        #pragma unroll
        for (int cc = 0; cc < 8; cc++) {
            const float* vp = &v_s[((buf * 8 + cc) * 4 + ohl) * VS + 2 * owl];
            float v0 = vp[0], v1 = vp[1], v2 = vp[2], v3 = vp[3];
            float y = 0.125f * (v0 + v3) + 0.375f * (v1 + v2);
            const float* wrow = w + ((t * 8 + cc) << 8) + oc0;
            #pragma unroll
            for (int i = 0; i < 32; i++)
                acc[i] = fmaf(wrow[i], y, acc[i]);
        }
        __syncthreads();
    }

    {
        size_t base = (((size_t)n * 256 + oc0) * 256 + (size_t)(oh0 + ohl)) * 256
                      + ow0 + owl;
        #pragma unroll
        for (int i = 0; i < 32; i++)
            out[base + (size_t)i * 65536] = acc[i];
    }
}

extern "C" void kernel_launch(void* const* d_in, const int* in_sizes, int n_in,
                              void* d_out, int out_size, void* d_ws, size_t ws_size,
                              hipStream_t stream) {
    const float* x = (const float*)d_in[0];
    const float* w = (const float*)d_in[1];
    float* out = (float*)d_out;

    const size_t need = 4ull * 128 * 256 * 256 * 4;   // 134,217,728 B for y
    if (ws_size >= need) {
        float* yws = (float*)d_ws;
        hipLaunchKernelGGL(fir_pass, dim3(16384), dim3(256), 0, stream, x, yws);
        hipLaunchKernelGGL(gemm_pass, dim3(1024, 4), dim3(512), 0, stream,
                           yws, w, out);
    } else {
        hipLaunchKernelGGL(fused_fallback, dim3(16, 64, 4), dim3(512), 0, stream,
                           x, w, out);
    }
}